// Round 1
// baseline (2477.449 us; speedup 1.0000x reference)
//
#include <hip/hip_runtime.h>

namespace {
constexpr int Bn = 2, Dn = 48, Hn = 320, Wn = 640;
constexpr int R = 2, K = 5, K2 = 25, C3 = 75;
constexpr int TW = 64, TH = 4;
constexpr int LW = TW + 2 * R;    // 68 floats per staged row
constexpr int LH = TH + 2 * R;    // 8 staged rows
constexpr int NT = TW * TH;       // 256 threads
constexpr int LTOT = LH * LW;     // 544 floats per plane slot
constexpr int LW2 = LW / 2;       // 34 float2 per row (margins are width-2, pair-aligned)
constexpr int LTOT2 = LH * LW2;   // 272 float2 per slot
constexpr int NCH2 = 2;           // float2 staging chunks: 256 + 16
constexpr int NSLOT = 4;          // LDS plane slots
}

// out[b,d,h,w] = sum_{ij in 5x5} w0*x[d] + w1*x[d-1] + w2*x[d+1], zero-padded.
// Sg(p) = sum_ij wg[ij]*win_p[ij]; out[d] = S0(d)+S1(d-1)+S2(d+1)
//   -> ONE 25-elem window per plane + 2 carry scalars.
//
// Pipeline (this revision): 3-deep VMEM coverage. Step p:
//   issue plane p+5 (global->reg, float2), read window p from LDS (75 FMAs),
//   commit plane p+2 (reg->LDS; its loads are 3 steps old), store out[p-1].
// Staging arrays rotate mod 4 (G[q%4] holds plane q) which matches the mod-4
// slot rotation -> clean 4-step unrolled loop, 48 % 4 == 0.
//
// KEY: barriers are lgkmcnt-only. __syncthreads() would emit
// s_waitcnt vmcnt(0) and drain the 3-step prefetch queue every 2 planes
// (the measured latency wall: 1.7 TB/s HBM, 32% VALU, nothing saturated).
// Cross-wave hazards are LDS-only; the counted vmcnt the compiler inserts
// before each commit's ds_write is the only VMEM wait we need.
__global__ __launch_bounds__(NT, 4)
void lga_pass(const float* __restrict__ x, const float* __restrict__ wt,
              float* __restrict__ out) {
    __shared__ __align__(16) float pl[NSLOT][LTOT];

    const int tx = threadIdx.x;          // 0..63 (w)
    const int ty = threadIdx.y;          // 0..3  (h)
    const int tid = ty * TW + tx;

    const int w0pix = blockIdx.x * TW;
    const int h0pix = blockIdx.y * TH;
    const int b = blockIdx.z;

    const int gw = w0pix + tx;
    const int gh = h0pix + ty;

    const size_t ps = (size_t)Hn * Wn;

    // ---- staging offsets (float2 granularity; OOB is always a full pair) ----
    int  soff2[NCH2];
    bool sval2[NCH2];
#pragma unroll
    for (int t = 0; t < NCH2; ++t) {
        int idx = tid + t * NT;              // float2 index within slot
        int rr = idx / LW2;
        int cc = idx - rr * LW2;
        int hh = h0pix - R + rr;
        int ww = w0pix - R + 2 * cc;         // even; pair {ww, ww+1}
        bool ok = (idx < LTOT2) && hh >= 0 && hh < Hn && ww >= 0 && ww < Wn;
        sval2[t] = ok;
        soff2[t] = ok ? ((hh * Wn + ww) >> 1) : 0;   // float2 offset
    }

    const float* xb = x + (size_t)b * Dn * ps;

    // ---- 75 per-pixel guidance weights -> registers (reused over 48 planes) ----
    float wr[C3];
    {
        const float* wp = wt + (size_t)b * C3 * ps + (size_t)gh * Wn + gw;
#pragma unroll
        for (int c = 0; c < C3; ++c) wr[c] = wp[(size_t)c * ps];
    }

    float* op = out + (size_t)b * Dn * ps + (size_t)gh * Wn + gw;
    const int lbase = ty * LW + tx;          // window base within a slot

    auto issue = [&](int p, float2 (&g)[NCH2]) {
        const float2* src = (const float2*)(xb + (size_t)p * ps);
        const bool pv = p < Dn;
#pragma unroll
        for (int t = 0; t < NCH2; ++t) {
            float2 v = make_float2(0.f, 0.f);
            if (pv && sval2[t]) v = src[soff2[t]];
            g[t] = v;
        }
    };
    auto commit = [&](int slot, const float2 (&g)[NCH2]) {
        float2* dst = reinterpret_cast<float2*>(pl[slot]);
#pragma unroll
        for (int t = 0; t < NCH2; ++t) {
            int idx = tid + t * NT;
            if (t == 0 || idx < LTOT2) dst[idx] = g[t];
        }
    };

    // lgkmcnt-only barrier: orders all LDS traffic, leaves global prefetches
    // in flight (counted vmcnt handles them at the consuming ds_write).
    auto sync_lds = [&]() {
        asm volatile("s_waitcnt lgkmcnt(0)\n\ts_barrier" ::: "memory");
    };

    float carry = 0.f, s1prev = 0.f;

    // one d-step; all slot/array roles are literals at call sites
    auto step = [&](int p, int sR, int sC,
                    float2 (&gI)[NCH2], const float2 (&gC)[NCH2]) {
        issue(p + 5, gI);                        // plane p+5 into flight
        float S0 = 0.f, S1 = 0.f, S2 = 0.f;
#pragma unroll
        for (int i = 0; i < K; ++i) {            // row-interleaved: 5 live vals
            float v0 = pl[sR][lbase + i * LW + 0];
            float v1 = pl[sR][lbase + i * LW + 1];
            float v2 = pl[sR][lbase + i * LW + 2];
            float v3 = pl[sR][lbase + i * LW + 3];
            float v4 = pl[sR][lbase + i * LW + 4];
            S0 += wr[i*K+0]*v0 + wr[i*K+1]*v1 + wr[i*K+2]*v2 + wr[i*K+3]*v3 + wr[i*K+4]*v4;
            S1 += wr[K2+i*K+0]*v0 + wr[K2+i*K+1]*v1 + wr[K2+i*K+2]*v2 + wr[K2+i*K+3]*v3 + wr[K2+i*K+4]*v4;
            S2 += wr[2*K2+i*K+0]*v0 + wr[2*K2+i*K+1]*v1 + wr[2*K2+i*K+2]*v2 + wr[2*K2+i*K+3]*v3 + wr[2*K2+i*K+4]*v4;
        }
        commit(sC, gC);                          // plane p+2 (issued at p-3)
        if (p > 0) { *op = carry + S2; op += ps; }
        carry = S0 + s1prev;
        s1prev = S1;
    };

    // prologue: planes 0,1 direct into slots 0,1; planes 2,3,4 in flight
    // (G[q%4] holds plane q: 2->G2, 3->G3, 4->G0; step 0 issues 5->G1)
    float2 G0[NCH2], G1[NCH2], G2[NCH2], G3[NCH2];
    {
        float2 t0[NCH2];
        issue(0, t0); commit(0, t0);
        issue(1, t0); commit(1, t0);
    }
    issue(2, G2);
    issue(3, G3);
    issue(4, G0);
    sync_lds();

    // step p: slotR = p%4, slotC = (p+2)%4, gI = G[(p+1)%4], gC = G[(p+2)%4]
    for (int d0 = 0; d0 < Dn; d0 += 4) {
        step(d0 + 0, 0, 2, G1, G2);
        step(d0 + 1, 1, 3, G2, G3);
        sync_lds();
        step(d0 + 2, 2, 0, G3, G0);
        step(d0 + 3, 3, 1, G0, G1);
        if (d0 + 4 < Dn) sync_lds();
    }
    // out[D-1] = S0(D-1) + S1(D-2)   (S2 of plane D is zero)
    *op = carry;
}

extern "C" void kernel_launch(void* const* d_in, const int* in_sizes, int n_in,
                              void* d_out, int out_size, void* d_ws, size_t ws_size,
                              hipStream_t stream) {
    const float* x = (const float*)d_in[0];
    const float* w = (const float*)d_in[1];
    // d_in[2] = radius (always 2 here; compile-time constant)
    float* out = (float*)d_out;
    float* tmp = (float*)d_ws;   // intermediate y (78.6 MB)

    dim3 block(TW, TH, 1);
    dim3 grid(Wn / TW, Hn / TH, Bn);

    lga_pass<<<grid, block, 0, stream>>>(x, w, tmp);
    lga_pass<<<grid, block, 0, stream>>>(tmp, w, out);
}

// Round 2
// 513.172 us; speedup vs baseline: 4.8277x; 4.8277x over previous
//
#include <hip/hip_runtime.h>

namespace {
constexpr int Bn = 2, Dn = 48, Hn = 320, Wn = 640;
constexpr int R = 2, K = 5, K2 = 25, C3 = 75;
constexpr int TW = 64, TH = 4;
constexpr int LW = TW + 2 * R;    // 68 floats per staged row
constexpr int LH = TH + 2 * R;    // 8 staged rows
constexpr int NT = TW * TH;       // 256 threads
constexpr int LTOT = LH * LW;     // 544 floats per plane slot
constexpr int LW2 = LW / 2;       // 34 float2 per row (margins are width-2, pair-aligned)
constexpr int LTOT2 = LH * LW2;   // 272 float2 per slot
constexpr int NCH2 = 2;           // float2 staging chunks: 256 + 16
constexpr int NSLOT = 4;          // LDS plane slots
}

// out[b,d,h,w] = sum_{ij in 5x5} w0*x[d] + w1*x[d-1] + w2*x[d+1], zero-padded.
// Sg(p) = sum_ij wg[ij]*win_p[ij]; out[d] = S0(d)+S1(d-1)+S2(d+1)
//   -> ONE 25-elem window per plane + 2 carry scalars.
//
// Pipeline: 3-deep VMEM coverage. Step p:
//   issue plane p+5 (global->reg, float2), read window p from LDS (75 FMAs),
//   commit plane p+2 (reg->LDS; its loads are 3 steps old), store out[p-1].
// Staging arrays rotate mod 4 (G[q%4] holds plane q), matching the mod-4
// slot rotation -> clean 4-step unrolled loop, 48 % 4 == 0.
//
// Barriers are lgkmcnt-only: __syncthreads() would emit s_waitcnt vmcnt(0)
// and drain the prefetch queue every 2 planes. Cross-wave hazards are
// LDS-only; the compiler's counted vmcnt before each commit's ds_write is
// the only VMEM wait needed.
//
// LAUNCH BOUNDS: (256,2) and nothing tighter. Live state is ~130 VGPRs
// (wr[75] + 4x float2[2] pipeline regs + addressing). Round-1 experiment
// with (256,4) capped VGPRs at 64 -> wr[] spilled to scratch -> FETCH
// 205MB->1.66GB, 7x slower. Register budget is the binding constraint.
__global__ __launch_bounds__(NT, 2)
void lga_pass(const float* __restrict__ x, const float* __restrict__ wt,
              float* __restrict__ out) {
    __shared__ __align__(16) float pl[NSLOT][LTOT];

    const int tx = threadIdx.x;          // 0..63 (w)
    const int ty = threadIdx.y;          // 0..3  (h)
    const int tid = ty * TW + tx;

    const int w0pix = blockIdx.x * TW;
    const int h0pix = blockIdx.y * TH;
    const int b = blockIdx.z;

    const int gw = w0pix + tx;
    const int gh = h0pix + ty;

    const size_t ps = (size_t)Hn * Wn;

    // ---- staging offsets (float2 granularity; OOB is always a full pair) ----
    int  soff2[NCH2];
    bool sval2[NCH2];
#pragma unroll
    for (int t = 0; t < NCH2; ++t) {
        int idx = tid + t * NT;              // float2 index within slot
        int rr = idx / LW2;
        int cc = idx - rr * LW2;
        int hh = h0pix - R + rr;
        int ww = w0pix - R + 2 * cc;         // even; pair {ww, ww+1}
        bool ok = (idx < LTOT2) && hh >= 0 && hh < Hn && ww >= 0 && ww < Wn;
        sval2[t] = ok;
        soff2[t] = ok ? ((hh * Wn + ww) >> 1) : 0;   // float2 offset
    }

    const float* xb = x + (size_t)b * Dn * ps;

    // ---- 75 per-pixel guidance weights -> registers (reused over 48 planes) ----
    float wr[C3];
    {
        const float* wp = wt + (size_t)b * C3 * ps + (size_t)gh * Wn + gw;
#pragma unroll
        for (int c = 0; c < C3; ++c) wr[c] = wp[(size_t)c * ps];
    }

    float* op = out + (size_t)b * Dn * ps + (size_t)gh * Wn + gw;
    const int lbase = ty * LW + tx;          // window base within a slot

    auto issue = [&](int p, float2 (&g)[NCH2]) {
        const float2* src = (const float2*)(xb + (size_t)p * ps);
        const bool pv = p < Dn;
#pragma unroll
        for (int t = 0; t < NCH2; ++t) {
            float2 v = make_float2(0.f, 0.f);
            if (pv && sval2[t]) v = src[soff2[t]];
            g[t] = v;
        }
    };
    auto commit = [&](int slot, const float2 (&g)[NCH2]) {
        float2* dst = reinterpret_cast<float2*>(pl[slot]);
#pragma unroll
        for (int t = 0; t < NCH2; ++t) {
            int idx = tid + t * NT;
            if (t == 0 || idx < LTOT2) dst[idx] = g[t];
        }
    };

    // lgkmcnt-only barrier: orders all LDS traffic, leaves global prefetches
    // in flight (counted vmcnt handles them at the consuming ds_write).
    auto sync_lds = [&]() {
        asm volatile("s_waitcnt lgkmcnt(0)\n\ts_barrier" ::: "memory");
    };

    float carry = 0.f, s1prev = 0.f;

    // one d-step; all slot/array roles are literals at call sites
    auto step = [&](int p, int sR, int sC,
                    float2 (&gI)[NCH2], const float2 (&gC)[NCH2]) {
        issue(p + 5, gI);                        // plane p+5 into flight
        float S0 = 0.f, S1 = 0.f, S2 = 0.f;
#pragma unroll
        for (int i = 0; i < K; ++i) {            // row-interleaved: 5 live vals
            float v0 = pl[sR][lbase + i * LW + 0];
            float v1 = pl[sR][lbase + i * LW + 1];
            float v2 = pl[sR][lbase + i * LW + 2];
            float v3 = pl[sR][lbase + i * LW + 3];
            float v4 = pl[sR][lbase + i * LW + 4];
            S0 += wr[i*K+0]*v0 + wr[i*K+1]*v1 + wr[i*K+2]*v2 + wr[i*K+3]*v3 + wr[i*K+4]*v4;
            S1 += wr[K2+i*K+0]*v0 + wr[K2+i*K+1]*v1 + wr[K2+i*K+2]*v2 + wr[K2+i*K+3]*v3 + wr[K2+i*K+4]*v4;
            S2 += wr[2*K2+i*K+0]*v0 + wr[2*K2+i*K+1]*v1 + wr[2*K2+i*K+2]*v2 + wr[2*K2+i*K+3]*v3 + wr[2*K2+i*K+4]*v4;
        }
        commit(sC, gC);                          // plane p+2 (issued at p-3)
        if (p > 0) { *op = carry + S2; op += ps; }
        carry = S0 + s1prev;
        s1prev = S1;
    };

    // prologue: planes 0,1 direct into slots 0,1; planes 2,3,4 in flight
    // (G[q%4] holds plane q: 2->G2, 3->G3, 4->G0; step 0 issues 5->G1)
    float2 G0[NCH2], G1[NCH2], G2[NCH2], G3[NCH2];
    {
        float2 t0[NCH2];
        issue(0, t0); commit(0, t0);
        issue(1, t0); commit(1, t0);
    }
    issue(2, G2);
    issue(3, G3);
    issue(4, G0);
    sync_lds();

    // step p: slotR = p%4, slotC = (p+2)%4, gI = G[(p+1)%4], gC = G[(p+2)%4]
    for (int d0 = 0; d0 < Dn; d0 += 4) {
        step(d0 + 0, 0, 2, G1, G2);
        step(d0 + 1, 1, 3, G2, G3);
        sync_lds();
        step(d0 + 2, 2, 0, G3, G0);
        step(d0 + 3, 3, 1, G0, G1);
        if (d0 + 4 < Dn) sync_lds();
    }
    // out[D-1] = S0(D-1) + S1(D-2)   (S2 of plane D is zero)
    *op = carry;
}

extern "C" void kernel_launch(void* const* d_in, const int* in_sizes, int n_in,
                              void* d_out, int out_size, void* d_ws, size_t ws_size,
                              hipStream_t stream) {
    const float* x = (const float*)d_in[0];
    const float* w = (const float*)d_in[1];
    // d_in[2] = radius (always 2 here; compile-time constant)
    float* out = (float*)d_out;
    float* tmp = (float*)d_ws;   // intermediate y (78.6 MB)

    dim3 block(TW, TH, 1);
    dim3 grid(Wn / TW, Hn / TH, Bn);

    lga_pass<<<grid, block, 0, stream>>>(x, w, tmp);
    lga_pass<<<grid, block, 0, stream>>>(tmp, w, out);
}

// Round 4
// 380.415 us; speedup vs baseline: 6.5125x; 1.3490x over previous
//
#include <hip/hip_runtime.h>

namespace {
constexpr int Bn = 2, Dn = 48, Hn = 320, Wn = 640;
constexpr int R = 2, K = 5, K2 = 25, C3 = 75;
constexpr int TW = 64, TH = 4;
constexpr int LW = TW + 2 * R;   // 68 floats per staged row
constexpr int LH = TH + 2 * R;   // 8 staged rows
constexpr int NT = TW * TH;      // 256 threads
constexpr int LTOT = LH * LW;    // 544 useful floats per plane slot
constexpr int LTOTP = 576;       // padded: 2 full 256-lane chunks + 1 full 64-lane chunk
constexpr int NSLOT = 8;         // LDS plane slots (8 * 2304 B = 18.4 KB)
}

// out[b,d,h,w] = sum_{ij in 5x5} w0*x[d] + w1*x[d-1] + w2*x[d+1], zero-padded.
// Sg(p) = sum_ij wg[ij]*win_p[ij]; out[d] = S0(d)+S1(d-1)+S2(d+1)
//   -> ONE 25-elem window per plane + 2 carry scalars.
//
// r4 (fixes r3's correctness bug):
//  * ALL DMAs run at full exec. Slot padded to 576; chunks 0,1 staged by all
//    waves, chunk 2 by wave 0 only (wave-uniform branch -> instruction simply
//    not issued by waves 1-3). No reliance on masked-lane DMA semantics.
//  * Spatial zero-padding folded into the WEIGHTS: threads zero wr[] taps
//    whose source pixel is off-image; staging sources are clamped to valid
//    addresses (border cells hold garbage * 0-weight = 0). Exact math.
//  * vmcnt counting is PER-WAVE (r3's bug: wave 0 issues 3 DMAs/plane,
//    waves 1-3 issue 2; BARRIER(12) under-waited for waves 1-3). Safe count
//    = min over waves of guaranteed-newer ops: steady state 4 planes x 2 = 8.
//    Tail: 4 (2 planes in flight), then 0. Stores retire in order and only
//    add strictness.
//
// LAUNCH BOUNDS: (256,2) and nothing tighter — (256,4) capped VGPR at 64,
// spilled wr[75], 13x traffic (round-1 disaster). Register budget binds.
#define BARRIER(N) \
    asm volatile("s_waitcnt vmcnt(" #N ") lgkmcnt(0)\n\ts_barrier" ::: "memory")

__global__ __launch_bounds__(NT, 2)
void lga_pass(const float* __restrict__ x, const float* __restrict__ wt,
              float* __restrict__ out) {
    __shared__ __align__(16) float pl[NSLOT][LTOTP];

    const int tx = threadIdx.x;          // 0..63 (w)
    const int ty = threadIdx.y;          // 0..3  (h)
    const int tid = ty * TW + tx;

    const int w0pix = blockIdx.x * TW;
    const int h0pix = blockIdx.y * TH;
    const int b = blockIdx.z;

    const int gw = w0pix + tx;
    const int gh = h0pix + ty;

    const size_t ps = (size_t)Hn * Wn;

    // ---- staging offsets, clamped to valid addresses (no masks) ----
    int soff[3];
#pragma unroll
    for (int t = 0; t < 3; ++t) {
        int idx = tid + t * NT;          // chunk 2 used only by wave 0 (idx 512..575)
        int rr = idx / LW;
        int cc = idx - rr * LW;
        int hh = h0pix - R + rr;
        int ww = w0pix - R + cc;
        bool ok = (idx < LTOT) && hh >= 0 && hh < Hn && ww >= 0 && ww < Wn;
        soff[t] = ok ? (hh * Wn + ww) : 0;   // clamp: garbage data, zero weight
    }

    const float* xb = x + (size_t)b * Dn * ps;
    const int wseg = tid & ~63;          // wave's linear LDS segment start

    // ---- 75 per-pixel guidance weights -> registers (reused over 48 planes),
    //      with off-image taps zeroed (replaces spatial zero-padding) ----
    float wr[C3];
    {
        const float* wp = wt + (size_t)b * C3 * ps + (size_t)gh * Wn + gw;
#pragma unroll
        for (int c = 0; c < C3; ++c) wr[c] = wp[(size_t)c * ps];
#pragma unroll
        for (int i = 0; i < K; ++i) {
            const int hh = gh + i - R;
            const bool vh = (hh >= 0) && (hh < Hn);
#pragma unroll
            for (int j = 0; j < K; ++j) {
                const int ww = gw + j - R;
                if (!(vh && ww >= 0 && ww < Wn)) {
                    wr[i * K + j] = 0.f;
                    wr[K2 + i * K + j] = 0.f;
                    wr[2 * K2 + i * K + j] = 0.f;
                }
            }
        }
    }

    float* op = out + (size_t)b * Dn * ps + (size_t)gh * Wn + gw;
    const int lbase = ty * LW + tx;      // window base within a slot (max 543 read)

    // Async DMA of plane p into slot. Full exec on every issued op:
    // waves issue chunks 0,1; wave 0 also issues chunk 2 (uniform branch).
    // LDS dest = wave-uniform base + lane*4 (linear tid order).
    auto dma = [&](int p, int slot) {
        if (p >= Dn) return;             // uniform scalar branch
        const float* src = xb + (size_t)p * ps;
        __builtin_amdgcn_global_load_lds(
            (const __attribute__((address_space(1))) void*)(src + soff[0]),
            (__attribute__((address_space(3))) void*)(&pl[slot][0 * NT + wseg]),
            4, 0, 0);
        __builtin_amdgcn_global_load_lds(
            (const __attribute__((address_space(1))) void*)(src + soff[1]),
            (__attribute__((address_space(3))) void*)(&pl[slot][1 * NT + wseg]),
            4, 0, 0);
        if (ty == 0) {                   // wave-uniform: only wave 0 issues
            __builtin_amdgcn_global_load_lds(
                (const __attribute__((address_space(1))) void*)(src + soff[2]),
                (__attribute__((address_space(3))) void*)(&pl[slot][2 * NT + tx]),
                4, 0, 0);
        }
    };

    float carry = 0.f, s1prev = 0.f;

    // one d-step; slot roles are literals at every call site
    auto step = [&](int p, int sR, int sD) {
        dma(p + 6, sD);                  // plane p+6 into flight (slot (p+6)%8)
        float S0 = 0.f, S1 = 0.f, S2 = 0.f;
#pragma unroll
        for (int i = 0; i < K; ++i) {    // row-interleaved: 5 live vals
            float v0 = pl[sR][lbase + i * LW + 0];
            float v1 = pl[sR][lbase + i * LW + 1];
            float v2 = pl[sR][lbase + i * LW + 2];
            float v3 = pl[sR][lbase + i * LW + 3];
            float v4 = pl[sR][lbase + i * LW + 4];
            S0 += wr[i*K+0]*v0 + wr[i*K+1]*v1 + wr[i*K+2]*v2 + wr[i*K+3]*v3 + wr[i*K+4]*v4;
            S1 += wr[K2+i*K+0]*v0 + wr[K2+i*K+1]*v1 + wr[K2+i*K+2]*v2 + wr[K2+i*K+3]*v3 + wr[K2+i*K+4]*v4;
            S2 += wr[2*K2+i*K+0]*v0 + wr[2*K2+i*K+1]*v1 + wr[2*K2+i*K+2]*v2 + wr[2*K2+i*K+3]*v3 + wr[2*K2+i*K+4]*v4;
        }
        if (p > 0) { *op = carry + S2; op += ps; }
        carry = S0 + s1prev;
        s1prev = S1;
    };

    // prologue: planes 0..5 -> slots 0..5; need planes 0,1 landed.
    // Per-wave newer ops (planes 2..5): waves 1-3 have 8, wave 0 has 12 -> 8.
#pragma unroll
    for (int q = 0; q < 6; ++q) dma(q, q);
    BARRIER(8);

    // steady state: pair {p,p+1} reads slots p%8,(p+1)%8 (DMA'd 6 steps ago),
    // issues planes p+6,p+7. Barrier must cover next pair's planes: newer ops
    // for the weakest wave = 4 planes x 2 = vmcnt(8).
    for (int d0 = 0; d0 < 40; d0 += 8) {
        step(d0 + 0, 0, 6); step(d0 + 1, 1, 7); BARRIER(8);
        step(d0 + 2, 2, 0); step(d0 + 3, 3, 1); BARRIER(8);
        step(d0 + 4, 4, 2); step(d0 + 5, 5, 3); BARRIER(8);
        step(d0 + 6, 6, 4); step(d0 + 7, 7, 5); BARRIER(8);
    }
    // tail (d0 = 40): prefetches run off the end of D, counts shrink
    step(40, 0, 6); step(41, 1, 7); BARRIER(8);   // planes 44..47 in flight
    step(42, 2, 0); step(43, 3, 1); BARRIER(4);   // planes 46,47 in flight
    step(44, 4, 2); step(45, 5, 3); BARRIER(0);   // drain
    step(46, 6, 4); step(47, 7, 5);
    // out[D-1] = S0(D-1) + S1(D-2)   (S2 of plane D is zero)
    *op = carry;
}

extern "C" void kernel_launch(void* const* d_in, const int* in_sizes, int n_in,
                              void* d_out, int out_size, void* d_ws, size_t ws_size,
                              hipStream_t stream) {
    const float* x = (const float*)d_in[0];
    const float* w = (const float*)d_in[1];
    // d_in[2] = radius (always 2 here; compile-time constant)
    float* out = (float*)d_out;
    float* tmp = (float*)d_ws;   // intermediate y (78.6 MB)

    dim3 block(TW, TH, 1);
    dim3 grid(Wn / TW, Hn / TH, Bn);

    lga_pass<<<grid, block, 0, stream>>>(x, w, tmp);
    lga_pass<<<grid, block, 0, stream>>>(tmp, w, out);
}